// Round 1
// baseline (1350.911 us; speedup 1.0000x reference)
//
#include <hip/hip_runtime.h>
#include <math.h>

#define BB 4
#define CC 64
#define OCC 64
#define HH 256
#define WW 256
#define HP 258
#define WP 258
#define NPIX (BB * HH * WW)          // 262144
#define CNT_F 262144.0f

// ---------------------------------------------------------------------------
// Kernel A: pad+transpose x (b,c,h,w) -> x_t (b, Hp, Wp, c), interior only.
// ---------------------------------------------------------------------------
__global__ __launch_bounds__(256) void pad_transpose(const float* __restrict__ x,
                                                     float* __restrict__ xt) {
    int blk = blockIdx.x;            // b*H*(W/64) = 4096
    int xchunk = blk & 3;
    int y = (blk >> 2) & 255;
    int b = blk >> 10;
    int tid = threadIdx.x;
    __shared__ float tile[64][65];
    int x0 = xchunk * 64;
    int col = tid & 63;
    int crow = tid >> 6;             // 0..3
    const float* xp = x + ((size_t)b * CC) * HH * WW + (size_t)y * WW + x0;
#pragma unroll
    for (int i = 0; i < 16; ++i) {
        int c = crow + i * 4;
        tile[c][col] = xp[(size_t)c * HH * WW + col];
    }
    __syncthreads();
    float* op = xt + (((size_t)b * HP + (y + 1)) * WP + (x0 + 1)) * CC;
#pragma unroll
    for (int i = 0; i < 16; ++i) {
        int xl = crow + i * 4;
        op[(size_t)xl * CC + col] = tile[col][xl];
    }
}

// ---------------------------------------------------------------------------
// Kernel A2: zero the padded border of x_t.
// Per batch: rows 0 & 257 (258 px each) + cols 0 & 257 for rows 1..256 -> 1028 px
// ---------------------------------------------------------------------------
__global__ void zero_border(float* __restrict__ xt) {
    int i = blockIdx.x * 256 + threadIdx.x;
    const int total = BB * 1028 * CC;
    if (i >= total) return;
    int c = i & 63;
    int p = (i >> 6) % 1028;
    int b = (i >> 6) / 1028;
    int yp, xp;
    if (p < 258)      { yp = 0;           xp = p; }
    else if (p < 516) { yp = 257;         xp = p - 258; }
    else if (p < 772) { yp = p - 516 + 1; xp = 0; }
    else              { yp = p - 772 + 1; xp = 257; }
    xt[(((size_t)b * HP + yp) * WP + xp) * CC + c] = 0.0f;
}

// ---------------------------------------------------------------------------
// Kernel W: reorder conv_w (oc, c, kh, kw) -> wt[c][n][oc]  (n = kh*3+kw)
// ---------------------------------------------------------------------------
__global__ void reorder_w(const float* __restrict__ cw, float* __restrict__ wt) {
    int i = blockIdx.x * 256 + threadIdx.x;
    if (i >= OCC * CC * 9) return;
    int oc = i & 63;
    int n = (i >> 6) % 9;
    int c = i / (64 * 9);
    wt[i] = cw[((size_t)oc * CC + c) * 9 + n];
}

// ---------------------------------------------------------------------------
// Kernel B: offset conv, 3x3, 64 -> 18 channels, pad 1, + bias.
// Output layout (b, 18, h, w). One block = one (b, y) row, thread = x.
// ---------------------------------------------------------------------------
__global__ __launch_bounds__(256) void offset_conv(const float* __restrict__ x,
                                                   const float* __restrict__ pw,
                                                   const float* __restrict__ pb,
                                                   float* __restrict__ off) {
    int blk = blockIdx.x;            // b*H + y
    int y = blk & 255;
    int b = blk >> 8;
    int tx = threadIdx.x;
    float acc[18];
#pragma unroll
    for (int j = 0; j < 18; ++j) acc[j] = 0.0f;
    const float* xb = x + (size_t)b * CC * HH * WW;
    bool ymv = y > 0, ypv = y < HH - 1;
    bool xmv = tx > 0, xpv = tx < WW - 1;
    for (int c = 0; c < CC; ++c) {
        const float* xc = xb + (size_t)c * HH * WW + (size_t)y * WW + tx;
        float v[9];
        v[0] = (ymv && xmv) ? xc[-WW - 1] : 0.0f;
        v[1] = ymv ? xc[-WW] : 0.0f;
        v[2] = (ymv && xpv) ? xc[-WW + 1] : 0.0f;
        v[3] = xmv ? xc[-1] : 0.0f;
        v[4] = xc[0];
        v[5] = xpv ? xc[1] : 0.0f;
        v[6] = (ypv && xmv) ? xc[WW - 1] : 0.0f;
        v[7] = ypv ? xc[WW] : 0.0f;
        v[8] = (ypv && xpv) ? xc[WW + 1] : 0.0f;
        const float* wc = pw + c * 9;   // pw[(j*64 + c)*9 + k]
#pragma unroll
        for (int j = 0; j < 18; ++j) {
#pragma unroll
            for (int k = 0; k < 9; ++k)
                acc[j] += wc[(size_t)j * CC * 9 + k] * v[k];
        }
    }
#pragma unroll
    for (int j = 0; j < 18; ++j)
        off[(((size_t)b * 18 + j) * HH + y) * WW + tx] = acc[j] + pb[j];
}

// ---------------------------------------------------------------------------
// Kernel C: deformable sampling + main contraction.
// One block = one (b, y) row, thread = pixel x, 64 output-channel accumulators.
// Writes PRE-BN output to out (b, 64, h, w).
// ---------------------------------------------------------------------------
__global__ __launch_bounds__(256) void deform_main(const float* __restrict__ xt,
                                                   const float* __restrict__ off,
                                                   const float* __restrict__ wt,
                                                   float* __restrict__ out) {
    int blk = blockIdx.x;            // b*H + y
    int y = blk & 255;
    int b = blk >> 8;
    int tx = threadIdx.x;

    float acc[64];
#pragma unroll
    for (int o = 0; o < 64; ++o) acc[o] = 0.0f;

    const float* offp = off + ((size_t)b * 18) * HH * WW + (size_t)y * WW + tx;
    const float* xb = xt + (size_t)b * HP * WP * CC;

#pragma unroll 1
    for (int n = 0; n < 9; ++n) {
        float pnx = (float)(n / 3 - 1);
        float pny = (float)(n % 3 - 1);
        float px = offp[(size_t)n * HH * WW] + (float)(y + 1) + pnx;
        float py = offp[(size_t)(n + 9) * HH * WW] + (float)(tx + 1) + pny;
        float fx = floorf(px), fy = floorf(py);
        float pxc = fminf(fmaxf(px, 0.0f), 257.0f);
        float pyc = fminf(fmaxf(py, 0.0f), 257.0f);
        int ltx = (int)fminf(fmaxf(fx, 0.0f), 257.0f);
        int lty = (int)fminf(fmaxf(fy, 0.0f), 257.0f);
        int rbx = (int)fminf(fmaxf(fx + 1.0f, 0.0f), 257.0f);
        int rby = (int)fminf(fmaxf(fy + 1.0f, 0.0f), 257.0f);
        float fltx = (float)ltx, flty = (float)lty;
        float frbx = (float)rbx, frby = (float)rby;
        float g_lt = (1.0f + (fltx - pxc)) * (1.0f + (flty - pyc));
        float g_rb = (1.0f - (frbx - pxc)) * (1.0f - (frby - pyc));
        float g_lb = (1.0f + (fltx - pxc)) * (1.0f - (frby - pyc));
        float g_rt = (1.0f - (frbx - pxc)) * (1.0f + (flty - pyc));
        const float4* p_lt = (const float4*)(xb + ((size_t)ltx * WP + lty) * CC);
        const float4* p_rb = (const float4*)(xb + ((size_t)rbx * WP + rby) * CC);
        const float4* p_lb = (const float4*)(xb + ((size_t)ltx * WP + rby) * CC);
        const float4* p_rt = (const float4*)(xb + ((size_t)rbx * WP + lty) * CC);
        const float* wn = wt + n * 64;   // wt[c*576 + n*64 + oc]
#pragma unroll 2
        for (int c4 = 0; c4 < 16; ++c4) {
            float4 vlt = p_lt[c4], vrb = p_rb[c4], vlb = p_lb[c4], vrt = p_rt[c4];
            float xv[4];
            xv[0] = g_lt * vlt.x + g_rb * vrb.x + g_lb * vlb.x + g_rt * vrt.x;
            xv[1] = g_lt * vlt.y + g_rb * vrb.y + g_lb * vlb.y + g_rt * vrt.y;
            xv[2] = g_lt * vlt.z + g_rb * vrb.z + g_lb * vlb.z + g_rt * vrt.z;
            xv[3] = g_lt * vlt.w + g_rb * vrb.w + g_lb * vlb.w + g_rt * vrt.w;
            const float* wbase = wn + (size_t)c4 * 4 * 576;
#pragma unroll
            for (int j = 0; j < 4; ++j) {
#pragma unroll
                for (int o = 0; o < 64; ++o)
                    acc[o] += wbase[(size_t)j * 576 + o] * xv[j];
            }
        }
    }

    float* ob = out + (((size_t)b * 64) * HH + y) * WW + tx;
#pragma unroll
    for (int o = 0; o < 64; ++o) ob[(size_t)o * HH * WW] = acc[o];
}

// ---------------------------------------------------------------------------
// Kernel D: per-channel sum / sumsq over (b, h, w). One block per (oc, b).
// ---------------------------------------------------------------------------
__global__ __launch_bounds__(256) void stats_kernel(const float* __restrict__ out,
                                                    float* __restrict__ stats) {
    int blk = blockIdx.x;            // oc*B + b
    int b = blk & 3;
    int oc = blk >> 2;
    const float* p = out + ((size_t)b * 64 + oc) * HH * WW;
    float s = 0.0f, q = 0.0f;
    for (int i = threadIdx.x; i < HH * WW; i += 256) {
        float v = p[i];
        s += v;
        q += v * v;
    }
#pragma unroll
    for (int d = 1; d < 64; d <<= 1) {
        s += __shfl_xor(s, d, 64);
        q += __shfl_xor(q, d, 64);
    }
    __shared__ float sm[8];
    int wave = threadIdx.x >> 6, lane = threadIdx.x & 63;
    if (lane == 0) { sm[wave] = s; sm[4 + wave] = q; }
    __syncthreads();
    if (threadIdx.x == 0) {
        float ts = sm[0] + sm[1] + sm[2] + sm[3];
        float tq = sm[4] + sm[5] + sm[6] + sm[7];
        atomicAdd(&stats[oc], ts);
        atomicAdd(&stats[64 + oc], tq);
    }
}

// ---------------------------------------------------------------------------
// Kernel E: BN (batch stats) + LeakyReLU(0.1), in-place on out. float4.
// ---------------------------------------------------------------------------
__global__ __launch_bounds__(256) void bn_leaky(float* __restrict__ out,
                                                const float* __restrict__ stats,
                                                const float* __restrict__ gamma,
                                                const float* __restrict__ beta) {
    int i = blockIdx.x * 256 + threadIdx.x;      // float4 index, 4194304 total
    int oc = (i >> 14) & 63;                     // (i*4 / 65536) % 64
    float mean = stats[oc] * (1.0f / CNT_F);
    float var = stats[64 + oc] * (1.0f / CNT_F) - mean * mean;
    float scale = gamma[oc] * rsqrtf(var + 1e-5f);
    float shift = beta[oc] - mean * scale;
    float4* o4 = (float4*)out;
    float4 v = o4[i];
    v.x = v.x * scale + shift; v.x = v.x > 0.0f ? v.x : 0.1f * v.x;
    v.y = v.y * scale + shift; v.y = v.y > 0.0f ? v.y : 0.1f * v.y;
    v.z = v.z * scale + shift; v.z = v.z > 0.0f ? v.z : 0.1f * v.z;
    v.w = v.w * scale + shift; v.w = v.w > 0.0f ? v.w : 0.1f * v.w;
    o4[i] = v;
}

// ---------------------------------------------------------------------------
extern "C" void kernel_launch(void* const* d_in, const int* in_sizes, int n_in,
                              void* d_out, int out_size, void* d_ws, size_t ws_size,
                              hipStream_t stream) {
    (void)in_sizes; (void)n_in; (void)out_size; (void)ws_size;
    const float* x     = (const float*)d_in[0];
    const float* pw    = (const float*)d_in[1];
    const float* pb    = (const float*)d_in[2];
    const float* cw    = (const float*)d_in[3];
    const float* gamma = (const float*)d_in[4];
    const float* beta  = (const float*)d_in[5];
    float* out = (float*)d_out;
    float* ws  = (float*)d_ws;

    float* xt    = ws;                       // 4*258*258*64 = 17,040,384 floats
    float* off   = xt + 17040384;            // 4*18*256*256 = 4,718,592 floats
    float* wt    = off + 4718592;            // 64*9*64      =     36,864 floats
    float* stats = wt + 36864;               // 128 floats

    hipMemsetAsync(stats, 0, 128 * sizeof(float), stream);
    pad_transpose<<<4096, 256, 0, stream>>>(x, xt);
    zero_border<<<(BB * 1028 * CC + 255) / 256, 256, 0, stream>>>(xt);
    reorder_w<<<(OCC * CC * 9 + 255) / 256, 256, 0, stream>>>(cw, wt);
    offset_conv<<<BB * HH, 256, 0, stream>>>(x, pw, pb, off);
    deform_main<<<BB * HH, 256, 0, stream>>>(xt, off, wt, out);
    stats_kernel<<<OCC * BB, 256, 0, stream>>>(out, stats);
    bn_leaky<<<NPIX * OCC / 4 / 256, 256, 0, stream>>>(out, stats, gamma, beta);
}

// Round 2
// 599.864 us; speedup vs baseline: 2.2520x; 2.2520x over previous
//
#include <hip/hip_runtime.h>
#include <math.h>

#define BB 4
#define CC 64
#define OCC 64
#define HH 256
#define WW 256
#define HP 258
#define WP 258
#define NPIX (BB * HH * WW)          // 262144
#define CNT_F 262144.0f

typedef __attribute__((ext_vector_type(8))) __bf16 bf16x8;
typedef __attribute__((ext_vector_type(4))) float f32x4;

// ---------------------------------------------------------------------------
// Kernel A: pad+transpose x (b,c,h,w) -> xt (b, Hp, Wp, c) in BF16, interior.
// ---------------------------------------------------------------------------
__global__ __launch_bounds__(256) void pad_transpose(const float* __restrict__ x,
                                                     __bf16* __restrict__ xt) {
    int blk = blockIdx.x;            // b*H*(W/64) = 4096
    int xchunk = blk & 3;
    int y = (blk >> 2) & 255;
    int b = blk >> 10;
    int tid = threadIdx.x;
    __shared__ float tile[64][65];
    int x0 = xchunk * 64;
    int col = tid & 63;
    int crow = tid >> 6;             // 0..3
    const float* xp = x + ((size_t)b * CC) * HH * WW + (size_t)y * WW + x0;
#pragma unroll
    for (int i = 0; i < 16; ++i) {
        int c = crow + i * 4;
        tile[c][col] = xp[(size_t)c * HH * WW + col];
    }
    __syncthreads();
    __bf16* op = xt + (((size_t)b * HP + (y + 1)) * WP + (x0 + 1)) * CC;
#pragma unroll
    for (int i = 0; i < 16; ++i) {
        int xl = crow + i * 4;
        op[(size_t)xl * CC + col] = (__bf16)tile[col][xl];
    }
}

// ---------------------------------------------------------------------------
// Kernel A2: zero the padded border of xt (bf16).
// ---------------------------------------------------------------------------
__global__ void zero_border(__bf16* __restrict__ xt) {
    int i = blockIdx.x * 256 + threadIdx.x;
    const int total = BB * 1028 * CC;
    if (i >= total) return;
    int c = i & 63;
    int p = (i >> 6) % 1028;
    int b = (i >> 6) / 1028;
    int yp, xp;
    if (p < 258)      { yp = 0;           xp = p; }
    else if (p < 516) { yp = 257;         xp = p - 258; }
    else if (p < 772) { yp = p - 516 + 1; xp = 0; }
    else              { yp = p - 772 + 1; xp = 257; }
    xt[(((size_t)b * HP + yp) * WP + xp) * CC + c] = (__bf16)0.0f;
}

// ---------------------------------------------------------------------------
// Kernel W: conv_w (oc,c,3,3) -> wtb[oc][k] bf16, k = n*64 + c  (n = kh*3+kw)
// ---------------------------------------------------------------------------
__global__ void reorder_w(const float* __restrict__ cw, __bf16* __restrict__ wtb) {
    int i = blockIdx.x * 256 + threadIdx.x;     // i = oc*576 + n*64 + c
    if (i >= OCC * CC * 9) return;
    int c = i & 63;
    int n = (i >> 6) % 9;
    int oc = i / 576;
    wtb[i] = (__bf16)cw[((size_t)oc * CC + c) * 9 + n];
}

// ---------------------------------------------------------------------------
// Kernel B: offset conv, 3x3, 64 -> 18 channels, pad 1, + bias. (unchanged)
// ---------------------------------------------------------------------------
__global__ __launch_bounds__(256) void offset_conv(const float* __restrict__ x,
                                                   const float* __restrict__ pw,
                                                   const float* __restrict__ pb,
                                                   float* __restrict__ off) {
    int blk = blockIdx.x;            // b*H + y
    int y = blk & 255;
    int b = blk >> 8;
    int tx = threadIdx.x;
    float acc[18];
#pragma unroll
    for (int j = 0; j < 18; ++j) acc[j] = 0.0f;
    const float* xb = x + (size_t)b * CC * HH * WW;
    bool ymv = y > 0, ypv = y < HH - 1;
    bool xmv = tx > 0, xpv = tx < WW - 1;
    for (int c = 0; c < CC; ++c) {
        const float* xc = xb + (size_t)c * HH * WW + (size_t)y * WW + tx;
        float v[9];
        v[0] = (ymv && xmv) ? xc[-WW - 1] : 0.0f;
        v[1] = ymv ? xc[-WW] : 0.0f;
        v[2] = (ymv && xpv) ? xc[-WW + 1] : 0.0f;
        v[3] = xmv ? xc[-1] : 0.0f;
        v[4] = xc[0];
        v[5] = xpv ? xc[1] : 0.0f;
        v[6] = (ypv && xmv) ? xc[WW - 1] : 0.0f;
        v[7] = ypv ? xc[WW] : 0.0f;
        v[8] = (ypv && xpv) ? xc[WW + 1] : 0.0f;
        const float* wc = pw + c * 9;   // pw[(j*64 + c)*9 + k]
#pragma unroll
        for (int j = 0; j < 18; ++j) {
#pragma unroll
            for (int k = 0; k < 9; ++k)
                acc[j] += wc[(size_t)j * CC * 9 + k] * v[k];
        }
    }
#pragma unroll
    for (int j = 0; j < 18; ++j)
        off[(((size_t)b * 18 + j) * HH + y) * WW + tx] = acc[j] + pb[j];
}

// ---------------------------------------------------------------------------
// Kernel C: deformable sampling (lane=channel, coalesced) + MFMA contraction.
// Block = 32 pixels (quarter row) x 64 oc, K = 576. 256 threads = 4 waves.
//   wave (mh = w&1, nh = w>>1): computes px[mh*16..+16) x oc[nh*32..+32)
// LDS: sA[32][584] bf16 (x_off tile, k = n*64+c), scratch (coords, then sC).
// Writes PRE-BN output to out (b, 64, h, w).
// ---------------------------------------------------------------------------
__global__ __launch_bounds__(256, 3) void deform_mfma(const __bf16* __restrict__ xt,
                                                      const float* __restrict__ off,
                                                      const __bf16* __restrict__ wtb,
                                                      float* __restrict__ out) {
    // XCD band swizzle: each XCD (round-robin over phys) gets a contiguous
    // range of logical blocks -> contiguous y band -> L2 locality.
    int phys = blockIdx.x;                    // 8192 blocks
    int blk = (phys & 7) * 1024 + (phys >> 3);
    int xq = blk & 7;
    int y  = (blk >> 3) & 255;
    int b  = blk >> 11;
    int x0 = xq * 32;
    int tid = threadIdx.x;
    int wave = tid >> 6, lane = tid & 63;

    __shared__ __attribute__((aligned(16))) __bf16 sA[32][584];  // 584 = 576+8 pad
    __shared__ float scratch[2304];           // cg[288*4] f32 | cb[288*4] int ; reused as sC[32][65]
    float* cg = scratch;
    int*   cb = (int*)(scratch + 1152);

    // ---- phase 0: coords + bilinear weights for 288 tasks (32 px x 9 n) ----
    for (int t = tid; t < 288; t += 256) {
        int n = t >> 5, p = t & 31;
        float offx = off[(((size_t)(b * 18 + n)) * HH + y) * WW + x0 + p];
        float offy = off[(((size_t)(b * 18 + n + 9)) * HH + y) * WW + x0 + p];
        float px = offx + (float)(y + 1) + (float)(n / 3 - 1);
        float py = offy + (float)(x0 + p + 1) + (float)(n % 3 - 1);
        float fx = floorf(px), fy = floorf(py);
        float pxc = fminf(fmaxf(px, 0.0f), 257.0f);
        float pyc = fminf(fmaxf(py, 0.0f), 257.0f);
        int ltx = (int)fminf(fmaxf(fx, 0.0f), 257.0f);
        int lty = (int)fminf(fmaxf(fy, 0.0f), 257.0f);
        int rbx = (int)fminf(fmaxf(fx + 1.0f, 0.0f), 257.0f);
        int rby = (int)fminf(fmaxf(fy + 1.0f, 0.0f), 257.0f);
        float dxl = 1.0f + ((float)ltx - pxc);
        float dxr = 1.0f - ((float)rbx - pxc);
        float dyl = 1.0f + ((float)lty - pyc);
        float dyr = 1.0f - ((float)rby - pyc);
        cg[t * 4 + 0] = dxl * dyl;                 // lt
        cg[t * 4 + 1] = dxr * dyr;                 // rb
        cg[t * 4 + 2] = dxl * dyr;                 // lb (ltx, rby)
        cg[t * 4 + 3] = dxr * dyl;                 // rt (rbx, lty)
        cb[t * 4 + 0] = (ltx * WP + lty) * CC;
        cb[t * 4 + 1] = (rbx * WP + rby) * CC;
        cb[t * 4 + 2] = (ltx * WP + rby) * CC;
        cb[t * 4 + 3] = (rbx * WP + lty) * CC;
    }
    __syncthreads();

    // ---- phase 1: gather, lane = channel (coalesced 128B per corner) ----
    const __bf16* xb = xt + (size_t)b * HP * WP * CC;
#pragma unroll 4
    for (int i = 0; i < 72; ++i) {
        int t = wave * 72 + i;
        float g0 = cg[t * 4 + 0], g1 = cg[t * 4 + 1];
        float g2 = cg[t * 4 + 2], g3 = cg[t * 4 + 3];
        float v0 = (float)xb[cb[t * 4 + 0] + lane];
        float v1 = (float)xb[cb[t * 4 + 1] + lane];
        float v2 = (float)xb[cb[t * 4 + 2] + lane];
        float v3 = (float)xb[cb[t * 4 + 3] + lane];
        float v = g0 * v0 + g1 * v1 + g2 * v2 + g3 * v3;
        int n = t >> 5, p = t & 31;
        sA[p][n * 64 + lane] = (__bf16)v;
    }
    __syncthreads();

    // ---- phase 2: MFMA over K=576 ----
    int mh = wave & 1, nh = wave >> 1;
    int m = lane & 15, q = lane >> 4;
    f32x4 acc0 = {0.0f, 0.0f, 0.0f, 0.0f};
    f32x4 acc1 = {0.0f, 0.0f, 0.0f, 0.0f};
    const __bf16* arow = &sA[mh * 16 + m][q * 8];
    const __bf16* b0p = wtb + (size_t)(nh * 32 + m) * 576 + q * 8;
    const __bf16* b1p = b0p + 16 * 576;
#pragma unroll
    for (int k0 = 0; k0 < 576; k0 += 32) {
        bf16x8 a  = *(const bf16x8*)(arow + k0);
        bf16x8 b0 = *(const bf16x8*)(b0p + k0);
        bf16x8 b1 = *(const bf16x8*)(b1p + k0);
        acc0 = __builtin_amdgcn_mfma_f32_16x16x32_bf16(a, b0, acc0, 0, 0, 0);
        acc1 = __builtin_amdgcn_mfma_f32_16x16x32_bf16(a, b1, acc1, 0, 0, 0);
    }

    // ---- epilogue: stage to LDS (scratch reused as sC[32][65]), write out ----
    // D layout (16x16x32): col(oc) = lane&15, row(px) = (lane>>4)*4 + r
    float* sC = scratch;
    {
        int ocl = nh * 32 + m;
        int pxb = mh * 16 + q * 4;
#pragma unroll
        for (int r = 0; r < 4; ++r) {
            sC[(pxb + r) * 65 + ocl]      = acc0[r];
            sC[(pxb + r) * 65 + ocl + 16] = acc1[r];
        }
    }
    __syncthreads();
    float* ob = out + (((size_t)b * OCC) * HH + y) * WW + x0;
    for (int i = tid; i < 2048; i += 256) {
        int oc = i >> 5, p = i & 31;
        ob[(size_t)oc * HH * WW + p] = sC[p * 65 + oc];
    }
}

// ---------------------------------------------------------------------------
// Kernel D: per-channel sum / sumsq over (b, h, w). One block per (oc, b).
// ---------------------------------------------------------------------------
__global__ __launch_bounds__(256) void stats_kernel(const float* __restrict__ out,
                                                    float* __restrict__ stats) {
    int blk = blockIdx.x;            // oc*B + b
    int b = blk & 3;
    int oc = blk >> 2;
    const float* p = out + ((size_t)b * OCC + oc) * HH * WW;
    float s = 0.0f, q = 0.0f;
    for (int i = threadIdx.x; i < HH * WW; i += 256) {
        float v = p[i];
        s += v;
        q += v * v;
    }
#pragma unroll
    for (int d = 1; d < 64; d <<= 1) {
        s += __shfl_xor(s, d, 64);
        q += __shfl_xor(q, d, 64);
    }
    __shared__ float sm[8];
    int wave = threadIdx.x >> 6, lane = threadIdx.x & 63;
    if (lane == 0) { sm[wave] = s; sm[4 + wave] = q; }
    __syncthreads();
    if (threadIdx.x == 0) {
        float ts = sm[0] + sm[1] + sm[2] + sm[3];
        float tq = sm[4] + sm[5] + sm[6] + sm[7];
        atomicAdd(&stats[oc], ts);
        atomicAdd(&stats[64 + oc], tq);
    }
}

// ---------------------------------------------------------------------------
// Kernel E: BN (batch stats) + LeakyReLU(0.1), in-place on out. float4.
// ---------------------------------------------------------------------------
__global__ __launch_bounds__(256) void bn_leaky(float* __restrict__ out,
                                                const float* __restrict__ stats,
                                                const float* __restrict__ gamma,
                                                const float* __restrict__ beta) {
    int i = blockIdx.x * 256 + threadIdx.x;      // float4 index
    int oc = (i >> 14) & 63;
    float mean = stats[oc] * (1.0f / CNT_F);
    float var = stats[64 + oc] * (1.0f / CNT_F) - mean * mean;
    float scale = gamma[oc] * rsqrtf(var + 1e-5f);
    float shift = beta[oc] - mean * scale;
    float4* o4 = (float4*)out;
    float4 v = o4[i];
    v.x = v.x * scale + shift; v.x = v.x > 0.0f ? v.x : 0.1f * v.x;
    v.y = v.y * scale + shift; v.y = v.y > 0.0f ? v.y : 0.1f * v.y;
    v.z = v.z * scale + shift; v.z = v.z > 0.0f ? v.z : 0.1f * v.z;
    v.w = v.w * scale + shift; v.w = v.w > 0.0f ? v.w : 0.1f * v.w;
    o4[i] = v;
}

// ---------------------------------------------------------------------------
extern "C" void kernel_launch(void* const* d_in, const int* in_sizes, int n_in,
                              void* d_out, int out_size, void* d_ws, size_t ws_size,
                              hipStream_t stream) {
    (void)in_sizes; (void)n_in; (void)out_size; (void)ws_size;
    const float* x     = (const float*)d_in[0];
    const float* pw    = (const float*)d_in[1];
    const float* pb    = (const float*)d_in[2];
    const float* cw    = (const float*)d_in[3];
    const float* gamma = (const float*)d_in[4];
    const float* beta  = (const float*)d_in[5];
    float* out = (float*)d_out;
    char* ws = (char*)d_ws;

    __bf16* xtb  = (__bf16*)ws;                       // 17,040,384 bf16 = 34,080,768 B
    float*  off  = (float*)(ws + 34080768);           // 4,718,592 f32   = 18,874,368 B
    __bf16* wtb  = (__bf16*)(ws + 34080768 + 18874368);          // 36,864 bf16 = 73,728 B
    float*  stats = (float*)(ws + 34080768 + 18874368 + 73728);  // 128 f32

    hipMemsetAsync(stats, 0, 128 * sizeof(float), stream);
    pad_transpose<<<4096, 256, 0, stream>>>(x, xtb);
    zero_border<<<(BB * 1028 * CC + 255) / 256, 256, 0, stream>>>(xtb);
    reorder_w<<<(OCC * CC * 9 + 255) / 256, 256, 0, stream>>>(cw, wtb);
    offset_conv<<<BB * HH, 256, 0, stream>>>(x, pw, pb, off);
    deform_mfma<<<8192, 256, 0, stream>>>(xtb, off, wtb, out);
    stats_kernel<<<OCC * BB, 256, 0, stream>>>(out, stats);
    bn_leaky<<<NPIX * OCC / 4 / 256, 256, 0, stream>>>(out, stats, gamma, beta);
}

// Round 3
// 516.541 us; speedup vs baseline: 2.6153x; 1.1613x over previous
//
#include <hip/hip_runtime.h>
#include <math.h>

#define BB 4
#define CC 64
#define OCC 64
#define HH 256
#define WW 256
#define HP 258
#define WP 258
#define NPIX (BB * HH * WW)          // 262144
#define CNT_F 262144.0f

typedef __attribute__((ext_vector_type(8))) __bf16 bf16x8;
typedef __attribute__((ext_vector_type(4))) float f32x4;

// ---------------------------------------------------------------------------
// Kernel A: pad+transpose x (b,c,h,w) -> xt (b, Hp, Wp, c) in BF16, interior.
// ---------------------------------------------------------------------------
__global__ __launch_bounds__(256) void pad_transpose(const float* __restrict__ x,
                                                     __bf16* __restrict__ xt) {
    int blk = blockIdx.x;            // b*H*(W/64) = 4096
    int xchunk = blk & 3;
    int y = (blk >> 2) & 255;
    int b = blk >> 10;
    int tid = threadIdx.x;
    __shared__ float tile[64][65];
    int x0 = xchunk * 64;
    int col = tid & 63;
    int crow = tid >> 6;             // 0..3
    const float* xp = x + ((size_t)b * CC) * HH * WW + (size_t)y * WW + x0;
#pragma unroll
    for (int i = 0; i < 16; ++i) {
        int c = crow + i * 4;
        tile[c][col] = xp[(size_t)c * HH * WW + col];
    }
    __syncthreads();
    __bf16* op = xt + (((size_t)b * HP + (y + 1)) * WP + (x0 + 1)) * CC;
#pragma unroll
    for (int i = 0; i < 16; ++i) {
        int xl = crow + i * 4;
        op[(size_t)xl * CC + col] = (__bf16)tile[col][xl];
    }
}

// ---------------------------------------------------------------------------
// Kernel A2: zero the padded border of xt (bf16).
// ---------------------------------------------------------------------------
__global__ void zero_border(__bf16* __restrict__ xt) {
    int i = blockIdx.x * 256 + threadIdx.x;
    const int total = BB * 1028 * CC;
    if (i >= total) return;
    int c = i & 63;
    int p = (i >> 6) % 1028;
    int b = (i >> 6) / 1028;
    int yp, xp;
    if (p < 258)      { yp = 0;           xp = p; }
    else if (p < 516) { yp = 257;         xp = p - 258; }
    else if (p < 772) { yp = p - 516 + 1; xp = 0; }
    else              { yp = p - 772 + 1; xp = 257; }
    xt[(((size_t)b * HP + yp) * WP + xp) * CC + c] = (__bf16)0.0f;
}

// ---------------------------------------------------------------------------
// Kernel W: reorder both weight tensors to bf16 [oc][k], k = n*64 + c.
//   wtb: main conv  (64 oc x 576)
//   pwb: offset conv (18 oc padded to 32 x 576)
// ---------------------------------------------------------------------------
__global__ void reorder_weights(const float* __restrict__ cw,
                                const float* __restrict__ pw,
                                __bf16* __restrict__ wtb,
                                __bf16* __restrict__ pwb) {
    int i = blockIdx.x * 256 + threadIdx.x;
    if (i < 36864) {                          // wtb[oc*576 + n*64 + c]
        int c = i & 63;
        int n = (i >> 6) % 9;
        int oc = i / 576;
        wtb[i] = (__bf16)cw[((size_t)oc * CC + c) * 9 + n];
    } else {
        int j = i - 36864;
        if (j >= 18432) return;               // pwb: 32 x 576
        int c = j & 63;
        int n = (j >> 6) % 9;
        int oc = j / 576;
        pwb[j] = (__bf16)(oc < 18 ? pw[((size_t)oc * CC + c) * 9 + n] : 0.0f);
    }
}

// ---------------------------------------------------------------------------
// Kernel B: offset conv via MFMA. Block = 32 px; im2col copy from xt
// (fixed integer taps, zero-pad already materialized) then K=576 MFMA.
// Writes off (b, 18, h, w) f32 (+bias).
// ---------------------------------------------------------------------------
__global__ __launch_bounds__(256, 3) void offset_mfma(const __bf16* __restrict__ xt,
                                                      const __bf16* __restrict__ pwb,
                                                      const float* __restrict__ pb,
                                                      float* __restrict__ off) {
    int phys = blockIdx.x;                    // 8192
    int blk = (phys & 7) * 1024 + (phys >> 3);
    int xq = blk & 7;
    int y  = (blk >> 3) & 255;
    int b  = blk >> 11;
    int x0 = xq * 32;
    int tid = threadIdx.x;
    int wave = tid >> 6, lane = tid & 63;
    int chp = lane & 31, half = lane >> 5;

    __shared__ __attribute__((aligned(16))) __bf16 sA[32][584];
    __shared__ float sC[32][33];

    // ---- staging: pure copy, 2 tasks (px,n) per round, dword per lane ----
    const char* xb = (const char*)xt + (size_t)b * HP * WP * CC * 2 + (size_t)chp * 4;
#pragma unroll 4
    for (int r = 0; r < 36; ++r) {
        int t = wave * 72 + r * 2 + half;      // 0..287
        int n = t >> 5, p = t & 31;
        int dy = n / 3, dx = n % 3;            // y+1+(dy-1) = y+dy
        int srcB = ((y + dy) * WP + (x0 + p + dx)) * CC * 2;
        unsigned d = *(const unsigned*)(xb + srcB);
        *(unsigned*)&sA[p][n * 64 + chp * 2] = d;
    }
    __syncthreads();

    // ---- MFMA: wave (mh, nh) -> px[mh*16..+16) x oc[nh*16..+16) ----
    int mh = wave & 1, nh = wave >> 1;
    int m = lane & 15, q = lane >> 4;
    f32x4 acc = {0.0f, 0.0f, 0.0f, 0.0f};
    const __bf16* arow = &sA[mh * 16 + m][q * 8];
    const __bf16* bp = pwb + (size_t)(nh * 16 + m) * 576 + q * 8;
#pragma unroll
    for (int k0 = 0; k0 < 576; k0 += 32) {
        bf16x8 a  = *(const bf16x8*)(arow + k0);
        bf16x8 bf = *(const bf16x8*)(bp + k0);
        acc = __builtin_amdgcn_mfma_f32_16x16x32_bf16(a, bf, acc, 0, 0, 0);
    }
    {
        int oc = nh * 16 + m;
        int pxb = mh * 16 + q * 4;
#pragma unroll
        for (int r = 0; r < 4; ++r) sC[pxb + r][oc] = acc[r];
    }
    __syncthreads();

    float* ob = off + ((size_t)(b * 18)) * HH * WW + (size_t)y * WW + x0;
    for (int i = tid; i < 576; i += 256) {
        int n = i >> 5, p = i & 31;
        ob[(size_t)n * HH * WW + p] = sC[p][n] + pb[n];
    }
}

// ---------------------------------------------------------------------------
// Kernel C: deformable sampling (2 ch/lane packed) + MFMA contraction.
// Block = 32 px x 64 oc, K = 576. Writes PRE-BN output to out (b, 64, h, w).
// ---------------------------------------------------------------------------
__global__ __launch_bounds__(256, 3) void deform_mfma(const __bf16* __restrict__ xt,
                                                      const float* __restrict__ off,
                                                      const __bf16* __restrict__ wtb,
                                                      float* __restrict__ out) {
    int phys = blockIdx.x;                    // 8192
    int blk = (phys & 7) * 1024 + (phys >> 3);
    int xq = blk & 7;
    int y  = (blk >> 3) & 255;
    int b  = blk >> 11;
    int x0 = xq * 32;
    int tid = threadIdx.x;
    int wave = tid >> 6, lane = tid & 63;
    int chp = lane & 31, half = lane >> 5;

    __shared__ __attribute__((aligned(16))) __bf16 sA[32][584];
    __shared__ __attribute__((aligned(16))) float scratch[2304]; // cg4|cb4, then sC[32][65]
    float* cg = scratch;
    int*   cb = (int*)(scratch + 1152);

    // ---- phase 0: coords + bilinear weights for 288 tasks (32 px x 9 n) ----
    for (int t = tid; t < 288; t += 256) {
        int n = t >> 5, p = t & 31;
        float offx = off[(((size_t)(b * 18 + n)) * HH + y) * WW + x0 + p];
        float offy = off[(((size_t)(b * 18 + n + 9)) * HH + y) * WW + x0 + p];
        float px = offx + (float)(y + 1) + (float)(n / 3 - 1);
        float py = offy + (float)(x0 + p + 1) + (float)(n % 3 - 1);
        float fx = floorf(px), fy = floorf(py);
        float pxc = fminf(fmaxf(px, 0.0f), 257.0f);
        float pyc = fminf(fmaxf(py, 0.0f), 257.0f);
        int ltx = (int)fminf(fmaxf(fx, 0.0f), 257.0f);
        int lty = (int)fminf(fmaxf(fy, 0.0f), 257.0f);
        int rbx = (int)fminf(fmaxf(fx + 1.0f, 0.0f), 257.0f);
        int rby = (int)fminf(fmaxf(fy + 1.0f, 0.0f), 257.0f);
        float dxl = 1.0f + ((float)ltx - pxc);
        float dxr = 1.0f - ((float)rbx - pxc);
        float dyl = 1.0f + ((float)lty - pyc);
        float dyr = 1.0f - ((float)rby - pyc);
        cg[t * 4 + 0] = dxl * dyl;                 // lt
        cg[t * 4 + 1] = dxr * dyr;                 // rb
        cg[t * 4 + 2] = dxl * dyr;                 // lb (ltx, rby)
        cg[t * 4 + 3] = dxr * dyl;                 // rt (rbx, lty)
        cb[t * 4 + 0] = ((ltx * WP + lty) * CC) * 2;   // byte offsets
        cb[t * 4 + 1] = ((rbx * WP + rby) * CC) * 2;
        cb[t * 4 + 2] = ((ltx * WP + rby) * CC) * 2;
        cb[t * 4 + 3] = ((rbx * WP + lty) * CC) * 2;
    }
    __syncthreads();

    // ---- phase 1: gather+blend, 2 ch/lane, 2 tasks per round ----
    const char* xbl = (const char*)xt + (size_t)b * HP * WP * CC * 2 + (size_t)chp * 4;
    const float4* cg4 = (const float4*)scratch;
    const int4*   cb4 = (const int4*)(scratch + 1152);
#pragma unroll 4
    for (int r = 0; r < 36; ++r) {
        int t = wave * 72 + r * 2 + half;
        float4 g = cg4[t];
        int4 cv = cb4[t];
        unsigned d0 = *(const unsigned*)(xbl + cv.x);
        unsigned d1 = *(const unsigned*)(xbl + cv.y);
        unsigned d2 = *(const unsigned*)(xbl + cv.z);
        unsigned d3 = *(const unsigned*)(xbl + cv.w);
        float lo = g.x * __builtin_bit_cast(float, d0 << 16)
                 + g.y * __builtin_bit_cast(float, d1 << 16)
                 + g.z * __builtin_bit_cast(float, d2 << 16)
                 + g.w * __builtin_bit_cast(float, d3 << 16);
        float hi = g.x * __builtin_bit_cast(float, d0 & 0xffff0000u)
                 + g.y * __builtin_bit_cast(float, d1 & 0xffff0000u)
                 + g.z * __builtin_bit_cast(float, d2 & 0xffff0000u)
                 + g.w * __builtin_bit_cast(float, d3 & 0xffff0000u);
        __bf16 rlo = (__bf16)lo, rhi = (__bf16)hi;
        ushort2 rv;
        rv.x = __builtin_bit_cast(unsigned short, rlo);
        rv.y = __builtin_bit_cast(unsigned short, rhi);
        int n = t >> 5, p = t & 31;
        *(ushort2*)&sA[p][n * 64 + chp * 2] = rv;
    }
    __syncthreads();

    // ---- phase 2: MFMA over K=576 ----
    int mh = wave & 1, nh = wave >> 1;
    int m = lane & 15, q = lane >> 4;
    f32x4 acc0 = {0.0f, 0.0f, 0.0f, 0.0f};
    f32x4 acc1 = {0.0f, 0.0f, 0.0f, 0.0f};
    const __bf16* arow = &sA[mh * 16 + m][q * 8];
    const __bf16* b0p = wtb + (size_t)(nh * 32 + m) * 576 + q * 8;
    const __bf16* b1p = b0p + 16 * 576;
#pragma unroll
    for (int k0 = 0; k0 < 576; k0 += 32) {
        bf16x8 a  = *(const bf16x8*)(arow + k0);
        bf16x8 b0 = *(const bf16x8*)(b0p + k0);
        bf16x8 b1 = *(const bf16x8*)(b1p + k0);
        acc0 = __builtin_amdgcn_mfma_f32_16x16x32_bf16(a, b0, acc0, 0, 0, 0);
        acc1 = __builtin_amdgcn_mfma_f32_16x16x32_bf16(a, b1, acc1, 0, 0, 0);
    }

    // ---- epilogue: stage to LDS (scratch reused as sC[32][65]), write out ----
    __syncthreads();                          // coords no longer needed
    float* sC = scratch;
    {
        int ocl = nh * 32 + m;
        int pxb = mh * 16 + q * 4;
#pragma unroll
        for (int r = 0; r < 4; ++r) {
            sC[(pxb + r) * 65 + ocl]      = acc0[r];
            sC[(pxb + r) * 65 + ocl + 16] = acc1[r];
        }
    }
    __syncthreads();
    float* ob = out + (((size_t)b * OCC) * HH + y) * WW + x0;
    for (int i = tid; i < 2048; i += 256) {
        int oc = i >> 5, p = i & 31;
        ob[(size_t)oc * HH * WW + p] = sC[p * 65 + oc];
    }
}

// ---------------------------------------------------------------------------
// Kernel D: per-channel sum / sumsq over (b, h, w). One block per (oc, b).
// ---------------------------------------------------------------------------
__global__ __launch_bounds__(256) void stats_kernel(const float* __restrict__ out,
                                                    float* __restrict__ stats) {
    int blk = blockIdx.x;            // oc*B + b
    int b = blk & 3;
    int oc = blk >> 2;
    const float* p = out + ((size_t)b * OCC + oc) * HH * WW;
    float s = 0.0f, q = 0.0f;
    for (int i = threadIdx.x; i < HH * WW; i += 256) {
        float v = p[i];
        s += v;
        q += v * v;
    }
#pragma unroll
    for (int d = 1; d < 64; d <<= 1) {
        s += __shfl_xor(s, d, 64);
        q += __shfl_xor(q, d, 64);
    }
    __shared__ float sm[8];
    int wave = threadIdx.x >> 6, lane = threadIdx.x & 63;
    if (lane == 0) { sm[wave] = s; sm[4 + wave] = q; }
    __syncthreads();
    if (threadIdx.x == 0) {
        float ts = sm[0] + sm[1] + sm[2] + sm[3];
        float tq = sm[4] + sm[5] + sm[6] + sm[7];
        atomicAdd(&stats[oc], ts);
        atomicAdd(&stats[64 + oc], tq);
    }
}

// ---------------------------------------------------------------------------
// Kernel E: BN (batch stats) + LeakyReLU(0.1), in-place on out. float4.
// ---------------------------------------------------------------------------
__global__ __launch_bounds__(256) void bn_leaky(float* __restrict__ out,
                                                const float* __restrict__ stats,
                                                const float* __restrict__ gamma,
                                                const float* __restrict__ beta) {
    int i = blockIdx.x * 256 + threadIdx.x;      // float4 index
    int oc = (i >> 14) & 63;
    float mean = stats[oc] * (1.0f / CNT_F);
    float var = stats[64 + oc] * (1.0f / CNT_F) - mean * mean;
    float scale = gamma[oc] * rsqrtf(var + 1e-5f);
    float shift = beta[oc] - mean * scale;
    float4* o4 = (float4*)out;
    float4 v = o4[i];
    v.x = v.x * scale + shift; v.x = v.x > 0.0f ? v.x : 0.1f * v.x;
    v.y = v.y * scale + shift; v.y = v.y > 0.0f ? v.y : 0.1f * v.y;
    v.z = v.z * scale + shift; v.z = v.z > 0.0f ? v.z : 0.1f * v.z;
    v.w = v.w * scale + shift; v.w = v.w > 0.0f ? v.w : 0.1f * v.w;
    o4[i] = v;
}

// ---------------------------------------------------------------------------
extern "C" void kernel_launch(void* const* d_in, const int* in_sizes, int n_in,
                              void* d_out, int out_size, void* d_ws, size_t ws_size,
                              hipStream_t stream) {
    (void)in_sizes; (void)n_in; (void)out_size; (void)ws_size;
    const float* x     = (const float*)d_in[0];
    const float* pw    = (const float*)d_in[1];
    const float* pb    = (const float*)d_in[2];
    const float* cw    = (const float*)d_in[3];
    const float* gamma = (const float*)d_in[4];
    const float* beta  = (const float*)d_in[5];
    float* out = (float*)d_out;
    char* ws = (char*)d_ws;

    __bf16* xtb  = (__bf16*)ws;                       // 34,080,768 B
    float*  off  = (float*)(ws + 34080768);           // 18,874,368 B
    __bf16* wtb  = (__bf16*)(ws + 34080768 + 18874368);            // 73,728 B
    __bf16* pwb  = (__bf16*)(ws + 34080768 + 18874368 + 73728);    // 36,864 B
    float*  stats = (float*)(ws + 34080768 + 18874368 + 73728 + 36864);

    hipMemsetAsync(stats, 0, 128 * sizeof(float), stream);
    pad_transpose<<<4096, 256, 0, stream>>>(x, xtb);
    zero_border<<<(BB * 1028 * CC + 255) / 256, 256, 0, stream>>>(xtb);
    reorder_weights<<<216, 256, 0, stream>>>(cw, pw, wtb, pwb);
    offset_mfma<<<8192, 256, 0, stream>>>(xtb, pwb, pb, off);
    deform_mfma<<<8192, 256, 0, stream>>>(xtb, off, wtb, out);
    stats_kernel<<<OCC * BB, 256, 0, stream>>>(out, stats);
    bn_leaky<<<NPIX * OCC / 4 / 256, 256, 0, stream>>>(out, stats, gamma, beta);
}

// Round 6
// 457.233 us; speedup vs baseline: 2.9545x; 1.1297x over previous
//
#include <hip/hip_runtime.h>
#include <math.h>

#define BB 4
#define CC 64
#define OCC 64
#define HH 256
#define WW 256
#define HP 258
#define WP 258
#define NPIX (BB * HH * WW)          // 262144
#define CNT_F 262144.0f

typedef __attribute__((ext_vector_type(8))) __bf16 bf16x8;
typedef __attribute__((ext_vector_type(4))) float f32x4;

// ---------------------------------------------------------------------------
// Kernel A: pad+transpose x (b,c,h,w) -> xt (b, Hp, Wp, c) in BF16, interior.
// (round-3 exact)
// ---------------------------------------------------------------------------
__global__ __launch_bounds__(256) void pad_transpose(const float* __restrict__ x,
                                                     __bf16* __restrict__ xt) {
    int blk = blockIdx.x;            // b*H*(W/64) = 4096
    int xchunk = blk & 3;
    int y = (blk >> 2) & 255;
    int b = blk >> 10;
    int tid = threadIdx.x;
    __shared__ float tile[64][65];
    int x0 = xchunk * 64;
    int col = tid & 63;
    int crow = tid >> 6;             // 0..3
    const float* xp = x + ((size_t)b * CC) * HH * WW + (size_t)y * WW + x0;
#pragma unroll
    for (int i = 0; i < 16; ++i) {
        int c = crow + i * 4;
        tile[c][col] = xp[(size_t)c * HH * WW + col];
    }
    __syncthreads();
    __bf16* op = xt + (((size_t)b * HP + (y + 1)) * WP + (x0 + 1)) * CC;
#pragma unroll
    for (int i = 0; i < 16; ++i) {
        int xl = crow + i * 4;
        op[(size_t)xl * CC + col] = (__bf16)tile[col][xl];
    }
}

// ---------------------------------------------------------------------------
// Kernel A2: zero the padded border of xt (bf16). (round-3 exact)
// ---------------------------------------------------------------------------
__global__ void zero_border(__bf16* __restrict__ xt) {
    int i = blockIdx.x * 256 + threadIdx.x;
    const int total = BB * 1028 * CC;
    if (i >= total) return;
    int c = i & 63;
    int p = (i >> 6) % 1028;
    int b = (i >> 6) / 1028;
    int yp, xp;
    if (p < 258)      { yp = 0;           xp = p; }
    else if (p < 516) { yp = 257;         xp = p - 258; }
    else if (p < 772) { yp = p - 516 + 1; xp = 0; }
    else              { yp = p - 772 + 1; xp = 257; }
    xt[(((size_t)b * HP + yp) * WP + xp) * CC + c] = (__bf16)0.0f;
}

// ---------------------------------------------------------------------------
// Kernel W: reorder both weight tensors to bf16 [oc][k], k = n*64 + c.
// (round-3 exact)
// ---------------------------------------------------------------------------
__global__ void reorder_weights(const float* __restrict__ cw,
                                const float* __restrict__ pw,
                                __bf16* __restrict__ wtb,
                                __bf16* __restrict__ pwb) {
    int i = blockIdx.x * 256 + threadIdx.x;
    if (i < 36864) {                          // wtb[oc*576 + n*64 + c]
        int c = i & 63;
        int n = (i >> 6) % 9;
        int oc = i / 576;
        wtb[i] = (__bf16)cw[((size_t)oc * CC + c) * 9 + n];
    } else {
        int j = i - 36864;
        if (j >= 18432) return;               // pwb: 32 x 576
        int c = j & 63;
        int n = (j >> 6) % 9;
        int oc = j / 576;
        pwb[j] = (__bf16)(oc < 18 ? pw[((size_t)oc * CC + c) * 9 + n] : 0.0f);
    }
}

// ---------------------------------------------------------------------------
// Kernel B: offset conv via MFMA with shifted-strip staging.
// Block = 32 px (quarter row). Stage 3 rows x 34 px x 64 ch of xt once;
// tap (dy,dx)'s A-fragment is a shifted window of the strip (no im2col dup).
// k-order (n outer, c inner) identical to round 3 -> bit-identical result.
// Writes off (b, 18, h, w) f32 (+bias).
// ---------------------------------------------------------------------------
__global__ __launch_bounds__(256, 6) void offset_strip(const __bf16* __restrict__ xt,
                                                       const __bf16* __restrict__ pwb,
                                                       const float* __restrict__ pb,
                                                       float* __restrict__ off) {
    int phys = blockIdx.x;                    // 8192
    int blk = (phys & 7) * 1024 + (phys >> 3);   // XCD band swizzle
    int xq = blk & 7;
    int y  = (blk >> 3) & 255;
    int b  = blk >> 11;
    int x0 = xq * 32;
    int tid = threadIdx.x;
    int wave = tid >> 6, lane = tid & 63;

    __shared__ __attribute__((aligned(16))) __bf16 sS[3][34][72];  // 14688 B
    __shared__ float sC[32][33];                                   //  4224 B

    // ---- staging: strip rows y..y+2, cols x0..x0+33 (padded coords) ----
    {
        const char* base = (const char*)xt + (size_t)b * HP * WP * CC * 2;
        for (int t = tid; t < 3264; t += 256) {      // 102 pos x 32 ch-pairs
            int pos = t >> 5, cp = t & 31;
            int r = pos / 34, j = pos - r * 34;
            unsigned d = *(const unsigned*)(base
                + (size_t)((y + r) * WP + (x0 + j)) * (CC * 2) + cp * 4);
            *(unsigned*)&sS[r][j][cp * 2] = d;
        }
    }
    __syncthreads();

    // ---- MFMA: wave (mh, nh) -> px[mh*16..+16) x oc[nh*16..+16), K=576 ----
    {
        int mh = wave & 1, nh = wave >> 1;
        int m = lane & 15, q = lane >> 4;
        int p_a = mh * 16 + m;                   // px row for A-fragment
        f32x4 acc = {0.0f, 0.0f, 0.0f, 0.0f};
        const __bf16* bp = pwb + (size_t)(nh * 16 + m) * 576 + q * 8;
#pragma unroll
        for (int n = 0; n < 9; ++n) {
            int dy = n / 3, dx = n - dy * 3;
            const __bf16* abase = &sS[dy][p_a + dx][q * 8];
#pragma unroll
            for (int h = 0; h < 2; ++h) {
                bf16x8 a  = *(const bf16x8*)(abase + h * 32);
                bf16x8 bv = *(const bf16x8*)(bp + n * 64 + h * 32);
                acc = __builtin_amdgcn_mfma_f32_16x16x32_bf16(a, bv, acc, 0, 0, 0);
            }
        }
        int oc = nh * 16 + m;
        int pxb = mh * 16 + q * 4;
#pragma unroll
        for (int r = 0; r < 4; ++r) sC[pxb + r][oc] = acc[r];
    }
    __syncthreads();

    float* ob = off + ((size_t)(b * 18)) * HH * WW + (size_t)y * WW + x0;
    for (int i = tid; i < 576; i += 256) {
        int n = i >> 5, p = i & 31;
        ob[(size_t)n * HH * WW + p] = sC[p][n] + pb[n];
    }
}

// ---------------------------------------------------------------------------
// Kernel C: deformable sampling + MFMA contraction, 16 px/block for occupancy.
// LDS 23.3 KB -> 7 blocks/CU (vs 3 at 32 px). Math bit-identical to round 3.
// Writes PRE-BN output to out (b, 64, h, w).
// ---------------------------------------------------------------------------
__global__ __launch_bounds__(256, 6) void deform_mfma16(const __bf16* __restrict__ xt,
                                                        const float* __restrict__ off,
                                                        const __bf16* __restrict__ wtb,
                                                        float* __restrict__ out) {
    int phys = blockIdx.x;                    // 16384
    int blk = (phys & 7) * 2048 + (phys >> 3);   // XCD band swizzle
    int xh = blk & 15;
    int y  = (blk >> 4) & 255;
    int b  = blk >> 12;
    int x0 = xh * 16;
    int tid = threadIdx.x;
    int wave = tid >> 6, lane = tid & 63;
    int chp = lane & 31, half = lane >> 5;

    __shared__ __attribute__((aligned(16))) __bf16 sA[16][584];   // 18688 B
    __shared__ __attribute__((aligned(16))) float scratch[1152];  //  4608 B
    float* cg = scratch;                       // 576 floats
    int*   cb = (int*)(scratch + 576);         // 576 ints

    // ---- phase 0: coords + bilinear weights, 144 tasks (16 px x 9 n) ----
    if (tid < 144) {
        int t = tid;
        int n = t >> 4, p = t & 15;
        float offx = off[(((size_t)(b * 18 + n)) * HH + y) * WW + x0 + p];
        float offy = off[(((size_t)(b * 18 + n + 9)) * HH + y) * WW + x0 + p];
        float px = offx + (float)(y + 1) + (float)(n / 3 - 1);
        float py = offy + (float)(x0 + p + 1) + (float)(n % 3 - 1);
        float fx = floorf(px), fy = floorf(py);
        float pxc = fminf(fmaxf(px, 0.0f), 257.0f);
        float pyc = fminf(fmaxf(py, 0.0f), 257.0f);
        int ltx = (int)fminf(fmaxf(fx, 0.0f), 257.0f);
        int lty = (int)fminf(fmaxf(fy, 0.0f), 257.0f);
        int rbx = (int)fminf(fmaxf(fx + 1.0f, 0.0f), 257.0f);
        int rby = (int)fminf(fmaxf(fy + 1.0f, 0.0f), 257.0f);
        float dxl = 1.0f + ((float)ltx - pxc);
        float dxr = 1.0f - ((float)rbx - pxc);
        float dyl = 1.0f + ((float)lty - pyc);
        float dyr = 1.0f - ((float)rby - pyc);
        cg[t * 4 + 0] = dxl * dyl;                 // lt
        cg[t * 4 + 1] = dxr * dyr;                 // rb
        cg[t * 4 + 2] = dxl * dyr;                 // lb (ltx, rby)
        cg[t * 4 + 3] = dxr * dyl;                 // rt (rbx, lty)
        cb[t * 4 + 0] = ((ltx * WP + lty) * CC) * 2;   // byte offsets
        cb[t * 4 + 1] = ((rbx * WP + rby) * CC) * 2;
        cb[t * 4 + 2] = ((ltx * WP + rby) * CC) * 2;
        cb[t * 4 + 3] = ((rbx * WP + lty) * CC) * 2;
    }
    __syncthreads();

    // ---- phase 1: gather+blend, 2 ch/lane, 2 tasks per round (round-3 exact) ----
    {
        const char* xbl = (const char*)xt + (size_t)b * HP * WP * CC * 2 + (size_t)chp * 4;
        const float4* cg4 = (const float4*)scratch;
        const int4*   cb4 = (const int4*)(scratch + 576);
#pragma unroll 3
        for (int r = 0; r < 18; ++r) {
            int t = wave * 36 + r * 2 + half;      // 0..143
            float4 g = cg4[t];
            int4 cv = cb4[t];
            unsigned d0 = *(const unsigned*)(xbl + cv.x);
            unsigned d1 = *(const unsigned*)(xbl + cv.y);
            unsigned d2 = *(const unsigned*)(xbl + cv.z);
            unsigned d3 = *(const unsigned*)(xbl + cv.w);
            float lo = g.x * __builtin_bit_cast(float, d0 << 16)
                     + g.y * __builtin_bit_cast(float, d1 << 16)
                     + g.z * __builtin_bit_cast(float, d2 << 16)
                     + g.w * __builtin_bit_cast(float, d3 << 16);
            float hi = g.x * __builtin_bit_cast(float, d0 & 0xffff0000u)
                     + g.y * __builtin_bit_cast(float, d1 & 0xffff0000u)
                     + g.z * __builtin_bit_cast(float, d2 & 0xffff0000u)
                     + g.w * __builtin_bit_cast(float, d3 & 0xffff0000u);
            __bf16 rlo = (__bf16)lo, rhi = (__bf16)hi;
            ushort2 rv;
            rv.x = __builtin_bit_cast(unsigned short, rlo);
            rv.y = __builtin_bit_cast(unsigned short, rhi);
            int n = t >> 4, p = t & 15;
            *(ushort2*)&sA[p][n * 64 + chp * 2] = rv;
        }
    }
    __syncthreads();

    // ---- phase 2: MFMA over K=576; wave -> 16 px x oc[wave*16..+16) ----
    int m = lane & 15, q = lane >> 4;
    f32x4 acc = {0.0f, 0.0f, 0.0f, 0.0f};
    {
        const __bf16* arow = &sA[m][q * 8];
        const __bf16* bp = wtb + (size_t)(wave * 16 + m) * 576 + q * 8;
#pragma unroll
        for (int k0 = 0; k0 < 576; k0 += 32) {
            bf16x8 a  = *(const bf16x8*)(arow + k0);
            bf16x8 bv = *(const bf16x8*)(bp + k0);
            acc = __builtin_amdgcn_mfma_f32_16x16x32_bf16(a, bv, acc, 0, 0, 0);
        }
    }

    // ---- epilogue: stage to LDS (scratch reused as sC[16][65]), write out ----
    __syncthreads();                          // cg/cb reads all done
    float* sC = scratch;
    {
        int ocl = wave * 16 + m;
        int pxb = q * 4;
#pragma unroll
        for (int r = 0; r < 4; ++r)
            sC[(pxb + r) * 65 + ocl] = acc[r];
    }
    __syncthreads();
    float* ob = out + (((size_t)b * OCC) * HH + y) * WW + x0;
    for (int i = tid; i < 1024; i += 256) {
        int oc = i >> 4, p = i & 15;
        ob[(size_t)oc * HH * WW + p] = sC[p * 65 + oc];
    }
}

// ---------------------------------------------------------------------------
// Kernel D: per-channel sum / sumsq over (b, h, w). (round-3 exact)
// ---------------------------------------------------------------------------
__global__ __launch_bounds__(256) void stats_kernel(const float* __restrict__ out,
                                                    float* __restrict__ stats) {
    int blk = blockIdx.x;            // oc*B + b
    int b = blk & 3;
    int oc = blk >> 2;
    const float* p = out + ((size_t)b * OCC + oc) * HH * WW;
    float s = 0.0f, q = 0.0f;
    for (int i = threadIdx.x; i < HH * WW; i += 256) {
        float v = p[i];
        s += v;
        q += v * v;
    }
#pragma unroll
    for (int d = 1; d < 64; d <<= 1) {
        s += __shfl_xor(s, d, 64);
        q += __shfl_xor(q, d, 64);
    }
    __shared__ float sm[8];
    int wave = threadIdx.x >> 6, lane = threadIdx.x & 63;
    if (lane == 0) { sm[wave] = s; sm[4 + wave] = q; }
    __syncthreads();
    if (threadIdx.x == 0) {
        float ts = sm[0] + sm[1] + sm[2] + sm[3];
        float tq = sm[4] + sm[5] + sm[6] + sm[7];
        atomicAdd(&stats[oc], ts);
        atomicAdd(&stats[64 + oc], tq);
    }
}

// ---------------------------------------------------------------------------
// Kernel E: BN (batch stats) + LeakyReLU(0.1), in-place on out. (round-3 exact)
// ---------------------------------------------------------------------------
__global__ __launch_bounds__(256) void bn_leaky(float* __restrict__ out,
                                                const float* __restrict__ stats,
                                                const float* __restrict__ gamma,
                                                const float* __restrict__ beta) {
    int i = blockIdx.x * 256 + threadIdx.x;      // float4 index
    int oc = (i >> 14) & 63;
    float mean = stats[oc] * (1.0f / CNT_F);
    float var = stats[64 + oc] * (1.0f / CNT_F) - mean * mean;
    float scale = gamma[oc] * rsqrtf(var + 1e-5f);
    float shift = beta[oc] - mean * scale;
    float4* o4 = (float4*)out;
    float4 v = o4[i];
    v.x = v.x * scale + shift; v.x = v.x > 0.0f ? v.x : 0.1f * v.x;
    v.y = v.y * scale + shift; v.y = v.y > 0.0f ? v.y : 0.1f * v.y;
    v.z = v.z * scale + shift; v.z = v.z > 0.0f ? v.z : 0.1f * v.z;
    v.w = v.w * scale + shift; v.w = v.w > 0.0f ? v.w : 0.1f * v.w;
    o4[i] = v;
}

// ---------------------------------------------------------------------------
extern "C" void kernel_launch(void* const* d_in, const int* in_sizes, int n_in,
                              void* d_out, int out_size, void* d_ws, size_t ws_size,
                              hipStream_t stream) {
    (void)in_sizes; (void)n_in; (void)out_size; (void)ws_size;
    const float* x     = (const float*)d_in[0];
    const float* pw    = (const float*)d_in[1];
    const float* pb    = (const float*)d_in[2];
    const float* cw    = (const float*)d_in[3];
    const float* gamma = (const float*)d_in[4];
    const float* beta  = (const float*)d_in[5];
    float* out = (float*)d_out;
    char* ws = (char*)d_ws;

    __bf16* xtb  = (__bf16*)ws;                       // 34,080,768 B
    float*  off  = (float*)(ws + 34080768);           // 18,874,368 B
    __bf16* wtb  = (__bf16*)(ws + 34080768 + 18874368);            // 73,728 B
    __bf16* pwb  = (__bf16*)(ws + 34080768 + 18874368 + 73728);    // 36,864 B
    float*  stats = (float*)(ws + 34080768 + 18874368 + 73728 + 36864);

    hipMemsetAsync(stats, 0, 128 * sizeof(float), stream);
    pad_transpose<<<4096, 256, 0, stream>>>(x, xtb);
    zero_border<<<(BB * 1028 * CC + 255) / 256, 256, 0, stream>>>(xtb);
    reorder_weights<<<216, 256, 0, stream>>>(cw, pw, wtb, pwb);
    offset_strip<<<8192, 256, 0, stream>>>(xtb, pwb, pb, off);
    deform_mfma16<<<16384, 256, 0, stream>>>(xtb, off, wtb, out);
    stats_kernel<<<OCC * BB, 256, 0, stream>>>(out, stats);
    bn_leaky<<<NPIX * OCC / 4 / 256, 256, 0, stream>>>(out, stats, gamma, beta);
}